// Round 1
// baseline (1401.599 us; speedup 1.0000x reference)
//
#include <hip/hip_runtime.h>
#include <hip/hip_bf16.h>

#define B_   512
#define N_   64
#define M_   12
#define F_   64
#define NF_  41
#define NODES (B_*N_)      /* 32768 */
#define ROWS  (NODES*M_)   /* 393216 */
#define NPB   8            /* nodes per block in k_gemm */
#define RPB   (NPB*M_)     /* 96 rows per block */
#define TSTR  108          /* padded (gathered 64 + nbr 41 -> 108) */
#define ASTR  68           /* atom row stride in LDS */
#define EPSV  1e-5f

/* workspace layout:
   [0,64):   double accum[8]  (s1, ss1, cnz1, cm1, s2, ss2, c2)
   [64,128): float scal[4]    (mu1, inv1, mu2, inv2)
   [128, 128 + ROWS*128*2):   bf16 total_gated (masked)              */
#define X_OFF 128

__device__ __forceinline__ float waveReduce(float v) {
#pragma unroll
  for (int off = 32; off > 0; off >>= 1) v += __shfl_down(v, off, 64);
  return v;
}

/* ---------------- K1: gather + concat + GEMM + mask + stats ------------- */
__global__ __launch_bounds__(256) void k_gemm(
    const float* __restrict__ atom, const float* __restrict__ nbr,
    const int* __restrict__ idx, const int* __restrict__ mask,
    const float* __restrict__ W, const float* __restrict__ bias,
    double* __restrict__ accum, __hip_bfloat16* __restrict__ xout)
{
  __shared__ float tot[RPB * TSTR];      // 41472 B
  __shared__ float atom_s[NPB * ASTR];   // 2176 B
  __shared__ int   idx_s[RPB];
  __shared__ float red[4][4];

  const int tid = threadIdx.x;
  const int g0  = blockIdx.x * NPB;      // first global node of block

  if (tid < RPB) idx_s[tid] = idx[g0 * M_ + tid];
  for (int e = tid; e < NPB * F_; e += 256) {
    int node = e >> 6, k = e & 63;
    atom_s[node * ASTR + k] = atom[(size_t)(g0 + node) * F_ + k];
  }
  __syncthreads();

  // stage gathered-atom (64) + nbr_fea (41) + zero pad (3) per row
  for (int e = tid; e < RPB * TSTR; e += 256) {
    int r = e / TSTR, k = e - r * TSTR;
    int node = r / M_;
    int g = g0 + node, b = g >> 6;
    float v;
    if (k < F_) {
      int nb = idx_s[r];
      v = atom[((size_t)(b * N_ + nb)) * F_ + k];
    } else if (k < F_ + NF_) {
      v = nbr[((size_t)(g0 * M_ + r)) * NF_ + (k - F_)];
    } else v = 0.f;
    tot[e] = v;
  }
  __syncthreads();

  const int rt = tid >> 4;           // 0..15 row-tile
  const int o0 = (tid & 15) * 8;     // output tile base
  const int node = rt >> 1;          // rows of a tile stay within one node
  const int r0 = rt * 6;

  // base[j] = bias[o0+j] + dot(atom_row, W[0:64, o0+j])  (shared by 6 rows)
  float base[8];
  {
    float4 ba = *(const float4*)&bias[o0];
    float4 bb = *(const float4*)&bias[o0 + 4];
    base[0]=ba.x; base[1]=ba.y; base[2]=ba.z; base[3]=ba.w;
    base[4]=bb.x; base[5]=bb.y; base[6]=bb.z; base[7]=bb.w;
  }
  for (int k = 0; k < F_; k += 4) {
    float4 t = *(const float4*)&atom_s[node * ASTR + k];
    float tk[4] = {t.x, t.y, t.z, t.w};
    float wv[32];
#pragma unroll
    for (int kk = 0; kk < 4; kk++) {
      float4 a = *(const float4*)&W[(k + kk) * 128 + o0];
      float4 b = *(const float4*)&W[(k + kk) * 128 + o0 + 4];
      wv[kk*8+0]=a.x; wv[kk*8+1]=a.y; wv[kk*8+2]=a.z; wv[kk*8+3]=a.w;
      wv[kk*8+4]=b.x; wv[kk*8+5]=b.y; wv[kk*8+6]=b.z; wv[kk*8+7]=b.w;
    }
#pragma unroll
    for (int kk = 0; kk < 4; kk++)
#pragma unroll
      for (int j = 0; j < 8; j++)
        base[j] = fmaf(tk[kk], wv[kk*8+j], base[j]);
  }

  float acc[6][8];
#pragma unroll
  for (int i = 0; i < 6; i++)
#pragma unroll
    for (int j = 0; j < 8; j++) acc[i][j] = 0.f;

  // main loop over gathered+nbr part: k' in [0,105), W row = 64 + k'
  for (int kp = 0; kp < 104; kp += 4) {
    float wv[32];
#pragma unroll
    for (int kk = 0; kk < 4; kk++) {
      float4 a = *(const float4*)&W[(F_ + kp + kk) * 128 + o0];
      float4 b = *(const float4*)&W[(F_ + kp + kk) * 128 + o0 + 4];
      wv[kk*8+0]=a.x; wv[kk*8+1]=a.y; wv[kk*8+2]=a.z; wv[kk*8+3]=a.w;
      wv[kk*8+4]=b.x; wv[kk*8+5]=b.y; wv[kk*8+6]=b.z; wv[kk*8+7]=b.w;
    }
#pragma unroll
    for (int i = 0; i < 6; i++) {
      float4 t = *(const float4*)&tot[(r0 + i) * TSTR + kp];
      float tk[4] = {t.x, t.y, t.z, t.w};
#pragma unroll
      for (int kk = 0; kk < 4; kk++)
#pragma unroll
        for (int j = 0; j < 8; j++)
          acc[i][j] = fmaf(tk[kk], wv[kk*8+j], acc[i][j]);
    }
  }
  { // tail k' = 104  (W row 168)
    float4 a = *(const float4*)&W[168 * 128 + o0];
    float4 b = *(const float4*)&W[168 * 128 + o0 + 4];
    float wv[8] = {a.x,a.y,a.z,a.w,b.x,b.y,b.z,b.w};
#pragma unroll
    for (int i = 0; i < 6; i++) {
      float t = tot[(r0 + i) * TSTR + 104];
#pragma unroll
      for (int j = 0; j < 8; j++) acc[i][j] = fmaf(t, wv[j], acc[i][j]);
    }
  }

  // epilogue: +base(+bias), mask, stats, bf16 store
  float s = 0.f, ss = 0.f, cz = 0.f, cm = 0.f;
#pragma unroll
  for (int i = 0; i < 6; i++) {
    size_t grow = (size_t)(g0 * M_) + r0 + i;
    const int4 mA = *(const int4*)&mask[grow * 128 + o0];
    const int4 mB = *(const int4*)&mask[grow * 128 + o0 + 4];
    int mv[8] = {mA.x, mA.y, mA.z, mA.w, mB.x, mB.y, mB.z, mB.w};
    unsigned short hb[8];
#pragma unroll
    for (int j = 0; j < 8; j++) {
      float y = acc[i][j] + base[j];
      y = mv[j] ? y : 0.f;
      s += y; ss += y * y;
      cz += (y != 0.f) ? 1.f : 0.f;
      cm += (float)mv[j];
      __hip_bfloat16 h = __float2bfloat16(y);
      hb[j] = *reinterpret_cast<const unsigned short*>(&h);
    }
    uint4 pk;
    pk.x = (unsigned)hb[0] | ((unsigned)hb[1] << 16);
    pk.y = (unsigned)hb[2] | ((unsigned)hb[3] << 16);
    pk.z = (unsigned)hb[4] | ((unsigned)hb[5] << 16);
    pk.w = (unsigned)hb[6] | ((unsigned)hb[7] << 16);
    *reinterpret_cast<uint4*>(&xout[grow * 128 + o0]) = pk;
  }

  float v0 = waveReduce(s), v1 = waveReduce(ss), v2 = waveReduce(cz), v3 = waveReduce(cm);
  int lane = tid & 63, wid = tid >> 6;
  if (lane == 0) { red[0][wid]=v0; red[1][wid]=v1; red[2][wid]=v2; red[3][wid]=v3; }
  __syncthreads();
  if (tid < 4) {
    float t = red[tid][0] + red[tid][1] + red[tid][2] + red[tid][3];
    atomicAdd(&accum[tid], (double)t);
  }
}

/* ---------------- K2: finalize BN1 stats ---------------- */
__global__ void k_fin1(const double* __restrict__ a, float* __restrict__ scal) {
  double s = a[0], ss = a[1], cnz = a[2], cm = a[3];
  double mu = 0.0, var = 0.0;
  if (cnz > 0.5) {
    mu = s / cnz;
    var = (ss - 2.0 * mu * s + mu * mu * cm) / cnz;
  }
  scal[0] = (float)mu;
  scal[1] = (float)(1.0 / sqrt(var + 1e-5));
}

/* ------- K3: BN1-apply + sigmoid*softplus + sum over M + stats2 ------- */
__global__ __launch_bounds__(256) void k_act(
    const __hip_bfloat16* __restrict__ x, const int* __restrict__ mask,
    const float* __restrict__ g1, const float* __restrict__ b1,
    const float* __restrict__ scal, double* __restrict__ accum,
    float* __restrict__ ns)
{
  __shared__ float red[3][4];
  int t = blockIdx.x * 256 + threadIdx.x;    // 0 .. NODES*64-1
  int o = t & 63;
  size_t g = (size_t)(t >> 6);
  float mu1 = scal[0], inv1 = scal[1];
  float kf = inv1 * g1[o];        float cf = b1[o]      - mu1 * kf;
  float kc = inv1 * g1[64 + o];   float cc = b1[64 + o] - mu1 * kc;
  size_t base = g * (M_ * 128) + o;
  float ssum = 0.f;
#pragma unroll
  for (int m = 0; m < M_; m++) {
    float xf = __bfloat162float(x[base + m * 128]);
    float xc = __bfloat162float(x[base + m * 128 + 64]);
    // x==0 <=> masked-out (stored exact 0); bn applies only where mask=1
    float yf = (xf != 0.f) ? fmaf(xf, kf, cf) : 0.f;
    float yc = (xc != 0.f) ? fmaf(xc, kc, cc) : 0.f;
    float sg = 1.f / (1.f + expf(-yf));
    float sp = fmaxf(yc, 0.f) + log1pf(expf(-fabsf(yc)));
    ssum += sg * sp;     // masked-out contributes sigmoid(0)*softplus(0), per ref
  }
  int mn = mask[g * (M_ * 128) + o];   // m_node = mask[b,n,0,o], o<64
  float v = mn ? ssum : 0.f;
  ns[t] = v;

  float s = v, ss = v * v, c = (v != 0.f) ? 1.f : 0.f;
  float v0 = waveReduce(s), v1 = waveReduce(ss), v2 = waveReduce(c);
  int lane = threadIdx.x & 63, wid = threadIdx.x >> 6;
  if (lane == 0) { red[0][wid] = v0; red[1][wid] = v1; red[2][wid] = v2; }
  __syncthreads();
  if (threadIdx.x < 3) {
    float r = red[threadIdx.x][0] + red[threadIdx.x][1] + red[threadIdx.x][2] + red[threadIdx.x][3];
    atomicAdd(&accum[4 + threadIdx.x], (double)r);
  }
}

/* ---------------- K4: finalize BN2 stats ---------------- */
__global__ void k_fin2(const double* __restrict__ a, float* __restrict__ scal) {
  double s = a[4], ss = a[5], c = a[6];
  double mu = 0.0, var = 0.0;
  if (c > 0.5) {
    mu = s / c;
    var = (ss - 2.0 * mu * s + mu * mu * c) / c;
  }
  scal[2] = (float)mu;
  scal[3] = (float)(1.0 / sqrt(var + 1e-5));
}

/* ---------------- K5: BN2-apply + residual softplus ---------------- */
__global__ __launch_bounds__(256) void k_out(
    const float* __restrict__ atom, const float* __restrict__ ns,
    const float* __restrict__ g2, const float* __restrict__ b2,
    const float* __restrict__ scal, float* __restrict__ out)
{
  int t = blockIdx.x * 256 + threadIdx.x;
  int o = t & 63;
  float v = ns[t];           // ns != 0 <=> m_node == 1 (gated strictly > 0)
  float r = 0.f;
  if (v != 0.f) {
    float bn = (v - scal[2]) * scal[3] * g2[o] + b2[o];
    float a = atom[t] + bn;
    r = fmaxf(a, 0.f) + log1pf(expf(-fabsf(a)));
  }
  out[t] = r;
}

extern "C" void kernel_launch(void* const* d_in, const int* in_sizes, int n_in,
                              void* d_out, int out_size, void* d_ws, size_t ws_size,
                              hipStream_t stream)
{
  const float* atom = (const float*)d_in[0];
  const float* nbr  = (const float*)d_in[1];
  const float* W    = (const float*)d_in[2];
  const float* bias = (const float*)d_in[3];
  const float* g1   = (const float*)d_in[4];
  const float* b1   = (const float*)d_in[5];
  const float* g2   = (const float*)d_in[6];
  const float* b2   = (const float*)d_in[7];
  const int*   idx  = (const int*)d_in[8];
  const int*   mask = (const int*)d_in[9];
  float* out = (float*)d_out;

  char* ws = (char*)d_ws;
  double* accum = (double*)ws;
  float*  scal  = (float*)(ws + 64);
  __hip_bfloat16* x = (__hip_bfloat16*)(ws + X_OFF);
  float* ns = out;   // reuse d_out as ns buffer: K3 writes all of it, K5 rewrites in place

  hipMemsetAsync(d_ws, 0, 64, stream);
  k_gemm<<<NODES / NPB, 256, 0, stream>>>(atom, nbr, idx, mask, W, bias, accum, x);
  k_fin1<<<1, 1, 0, stream>>>(accum, scal);
  k_act<<<(NODES * F_) / 256, 256, 0, stream>>>(x, mask, g1, b1, scal, accum, ns);
  k_fin2<<<1, 1, 0, stream>>>(accum, scal);
  k_out<<<(NODES * F_) / 256, 256, 0, stream>>>(atom, ns, g2, b2, scal, out);
}

// Round 2
// 498.302 us; speedup vs baseline: 2.8127x; 2.8127x over previous
//
#include <hip/hip_runtime.h>
#include <hip/hip_bf16.h>

#define B_   512
#define N_   64
#define M_   12
#define F_   64
#define NF_  41
#define NODES (B_*N_)      /* 32768 */
#define ROWS  (NODES*M_)   /* 393216 */
#define NPB   8            /* nodes per block in k_gemm */
#define RPB   (NPB*M_)     /* 96 rows per block */
#define KTOT  169
#define KPAD  192          /* 6 chunks of 32 */
#define ASTR  200          /* LDS row stride in bf16: bank-even for b128 frags */

typedef __bf16 bf16x8 __attribute__((ext_vector_type(8)));
typedef float  f32x4  __attribute__((ext_vector_type(4)));

/* workspace layout:
   [0,64):        double accum[8]  (s1, ss1, cnz1, cm1, s2, ss2, c2)
   [64,128):      float scal[4]    (mu1, inv1, mu2, inv2)
   [128,49280):   bf16 Wf — fragment-ordered W  (6*8*64*8 elems)
   [49280, +ROWS*128*2): bf16 total_gated (masked)                  */
#define WF_OFF 128
#define X_OFF  49280

__device__ __forceinline__ float waveReduce(float v) {
#pragma unroll
  for (int off = 32; off > 0; off >>= 1) v += __shfl_down(v, off, 64);
  return v;
}

/* ------- K0: W (fp32, row-major 169x128) -> fragment-ordered bf16 ------- */
/* Wf[kc][nt][lane][j] = W[kc*32 + (lane>>4)*8 + j][nt*16 + (lane&15)], 0-pad k>=169 */
__global__ void k_wprep(const float* __restrict__ W, __bf16* __restrict__ Wf) {
  int t = blockIdx.x * 256 + threadIdx.x;
  if (t >= 6 * 8 * 64) return;
  int lane = t & 63, nt = (t >> 6) & 7, kc = t >> 9;
  int n  = nt * 16 + (lane & 15);
  int k0 = kc * 32 + (lane >> 4) * 8;
  bf16x8 v;
#pragma unroll
  for (int j = 0; j < 8; j++) {
    int k = k0 + j;
    v[j] = (k < KTOT) ? (__bf16)W[k * 128 + n] : (__bf16)0.f;
  }
  *reinterpret_cast<bf16x8*>(&Wf[(size_t)t * 8]) = v;
}

/* ---------------- K1: gather + concat + MFMA GEMM + mask + stats ------------- */
__global__ __launch_bounds__(256, 4) void k_gemm(
    const float* __restrict__ atom, const float* __restrict__ nbr,
    const int* __restrict__ idx, const int* __restrict__ mask,
    const __bf16* __restrict__ Wf, const float* __restrict__ bias,
    double* __restrict__ accum, __bf16* __restrict__ xout)
{
  __shared__ __bf16 As[RPB * ASTR];   // 38400 B
  __shared__ int    idx_s[RPB];
  __shared__ float  red[4][4];

  const int tid = threadIdx.x;
  const int g0  = blockIdx.x * NPB;
  const int bb  = (g0 >> 6) << 6;     // b * N_  (block never crosses a batch)

  if (tid < RPB) idx_s[tid] = idx[g0 * M_ + tid];
  __syncthreads();

  // stage own-atom part, k in [0,64): rows duplicate node's atom row
  for (int e = tid; e < RPB * 16; e += 256) {
    int r = e >> 4, k4 = e & 15;
    int node = r / M_;
    float4 v = *(const float4*)&atom[(size_t)(g0 + node) * F_ + k4 * 4];
    __bf16 h[4] = {(__bf16)v.x, (__bf16)v.y, (__bf16)v.z, (__bf16)v.w};
    *reinterpret_cast<uint2*>(&As[r * ASTR + k4 * 4]) = *reinterpret_cast<uint2*>(h);
  }
  // stage gathered-atom part, k in [64,128)
  for (int e = tid; e < RPB * 16; e += 256) {
    int r = e >> 4, k4 = e & 15;
    float4 v = *(const float4*)&atom[(size_t)(bb + idx_s[r]) * F_ + k4 * 4];
    __bf16 h[4] = {(__bf16)v.x, (__bf16)v.y, (__bf16)v.z, (__bf16)v.w};
    *reinterpret_cast<uint2*>(&As[r * ASTR + 64 + k4 * 4]) = *reinterpret_cast<uint2*>(h);
  }
  // stage nbr_fea part, k in [128,169)
  for (int e = tid; e < RPB * NF_; e += 256) {
    int r = e / NF_, k = e - r * NF_;
    As[r * ASTR + 128 + k] = (__bf16)nbr[(size_t)(g0 * M_ + r) * NF_ + k];
  }
  // zero pad k in [169,200)
  for (int e = tid; e < RPB * 32; e += 256) {
    int r = e >> 5, k = 168 + (e & 31);
    if (k >= KTOT) As[r * ASTR + k] = (__bf16)0.f;
  }
  __syncthreads();

  const int w    = tid >> 6;          // wave id: owns nt = {2w, 2w+1}
  const int lane = tid & 63;
  const int nlo  = lane & 15;
  const int quad = lane >> 4;

  f32x4 acc[6][2];
#pragma unroll
  for (int mt = 0; mt < 6; mt++)
#pragma unroll
    for (int j = 0; j < 2; j++) acc[mt][j] = (f32x4){0.f, 0.f, 0.f, 0.f};

#pragma unroll
  for (int kc = 0; kc < 6; kc++) {
    bf16x8 bf[2];
#pragma unroll
    for (int j = 0; j < 2; j++) {
      int nt = 2 * w + j;
      bf[j] = *reinterpret_cast<const bf16x8*>(&Wf[(size_t)(((kc * 8 + nt) * 64) + lane) * 8]);
    }
#pragma unroll
    for (int mt = 0; mt < 6; mt++) {
      bf16x8 af = *reinterpret_cast<const bf16x8*>(
          &As[(mt * 16 + nlo) * ASTR + kc * 32 + quad * 8]);
#pragma unroll
      for (int j = 0; j < 2; j++)
        acc[mt][j] = __builtin_amdgcn_mfma_f32_16x16x32_bf16(af, bf[j], acc[mt][j], 0, 0, 0);
    }
  }

  // epilogue: +bias, mask, stats, bf16 store
  float s = 0.f, ss = 0.f, cz = 0.f, cm = 0.f;
  float bv[2];
#pragma unroll
  for (int j = 0; j < 2; j++) bv[j] = bias[(2 * w + j) * 16 + nlo];

#pragma unroll
  for (int mt = 0; mt < 6; mt++) {
#pragma unroll
    for (int reg = 0; reg < 4; reg++) {
      int rb = mt * 16 + quad * 4 + reg;
      size_t grow = (size_t)(g0 * M_) + rb;
#pragma unroll
      for (int j = 0; j < 2; j++) {
        int col = (2 * w + j) * 16 + nlo;
        int mv = mask[grow * 128 + col];
        float y = acc[mt][j][reg] + bv[j];
        y = mv ? y : 0.f;
        s += y; ss += y * y;
        cz += (y != 0.f) ? 1.f : 0.f;
        cm += (float)mv;
        xout[grow * 128 + col] = (__bf16)y;
      }
    }
  }

  float v0 = waveReduce(s), v1 = waveReduce(ss), v2 = waveReduce(cz), v3 = waveReduce(cm);
  if (lane == 0) { red[0][w] = v0; red[1][w] = v1; red[2][w] = v2; red[3][w] = v3; }
  __syncthreads();
  if (tid < 4) {
    float t = red[tid][0] + red[tid][1] + red[tid][2] + red[tid][3];
    atomicAdd(&accum[tid], (double)t);
  }
}

/* ---------------- K2: finalize BN1 stats ---------------- */
__global__ void k_fin1(const double* __restrict__ a, float* __restrict__ scal) {
  double s = a[0], ss = a[1], cnz = a[2], cm = a[3];
  double mu = 0.0, var = 0.0;
  if (cnz > 0.5) {
    mu = s / cnz;
    var = (ss - 2.0 * mu * s + mu * mu * cm) / cnz;
  }
  scal[0] = (float)mu;
  scal[1] = (float)(1.0 / sqrt(var + 1e-5));
}

/* ------- K3: BN1-apply + sigmoid*softplus + sum over M + stats2 ------- */
__global__ __launch_bounds__(256) void k_act(
    const __bf16* __restrict__ x, const int* __restrict__ mask,
    const float* __restrict__ g1, const float* __restrict__ b1,
    const float* __restrict__ scal, double* __restrict__ accum,
    float* __restrict__ ns)
{
  __shared__ float red[3][4];
  int t = blockIdx.x * 256 + threadIdx.x;    // 0 .. NODES*64-1
  int o = t & 63;
  size_t g = (size_t)(t >> 6);
  float mu1 = scal[0], inv1 = scal[1];
  float kf = inv1 * g1[o];        float cf = b1[o]      - mu1 * kf;
  float kc = inv1 * g1[64 + o];   float cc = b1[64 + o] - mu1 * kc;
  size_t base = g * (M_ * 128) + o;
  float ssum = 0.f;
#pragma unroll
  for (int m = 0; m < M_; m++) {
    float xf = (float)x[base + m * 128];
    float xc = (float)x[base + m * 128 + 64];
    // x==0 <=> masked-out (stored exact 0); bn applies only where mask=1
    float yf = (xf != 0.f) ? fmaf(xf, kf, cf) : 0.f;
    float yc = (xc != 0.f) ? fmaf(xc, kc, cc) : 0.f;
    float sg = __builtin_amdgcn_rcpf(1.f + __expf(-yf));
    float sp = fmaxf(yc, 0.f) + __logf(1.f + __expf(-fabsf(yc)));
    ssum += sg * sp;     // masked-out contributes sigmoid(0)*softplus(0), per ref
  }
  int mn = mask[g * (M_ * 128) + o];   // m_node = mask[b,n,0,o], o<64
  float v = mn ? ssum : 0.f;
  ns[t] = v;

  float s = v, ss = v * v, c = (v != 0.f) ? 1.f : 0.f;
  float v0 = waveReduce(s), v1 = waveReduce(ss), v2 = waveReduce(c);
  int lane = threadIdx.x & 63, wid = threadIdx.x >> 6;
  if (lane == 0) { red[0][wid] = v0; red[1][wid] = v1; red[2][wid] = v2; }
  __syncthreads();
  if (threadIdx.x < 3) {
    float r = red[threadIdx.x][0] + red[threadIdx.x][1] + red[threadIdx.x][2] + red[threadIdx.x][3];
    atomicAdd(&accum[4 + threadIdx.x], (double)r);
  }
}

/* ---------------- K4: finalize BN2 stats ---------------- */
__global__ void k_fin2(const double* __restrict__ a, float* __restrict__ scal) {
  double s = a[4], ss = a[5], c = a[6];
  double mu = 0.0, var = 0.0;
  if (c > 0.5) {
    mu = s / c;
    var = (ss - 2.0 * mu * s + mu * mu * c) / c;
  }
  scal[2] = (float)mu;
  scal[3] = (float)(1.0 / sqrt(var + 1e-5));
}

/* ---------------- K5: BN2-apply + residual softplus ---------------- */
__global__ __launch_bounds__(256) void k_out(
    const float* __restrict__ atom, const float* __restrict__ ns,
    const float* __restrict__ g2, const float* __restrict__ b2,
    const float* __restrict__ scal, float* __restrict__ out)
{
  int t = blockIdx.x * 256 + threadIdx.x;
  int o = t & 63;
  float v = ns[t];           // ns != 0 <=> m_node == 1 (gated strictly > 0)
  float r = 0.f;
  if (v != 0.f) {
    float bn = (v - scal[2]) * scal[3] * g2[o] + b2[o];
    float a = atom[t] + bn;
    r = fmaxf(a, 0.f) + __logf(1.f + __expf(-fabsf(a)));
  }
  out[t] = r;
}

extern "C" void kernel_launch(void* const* d_in, const int* in_sizes, int n_in,
                              void* d_out, int out_size, void* d_ws, size_t ws_size,
                              hipStream_t stream)
{
  const float* atom = (const float*)d_in[0];
  const float* nbr  = (const float*)d_in[1];
  const float* W    = (const float*)d_in[2];
  const float* bias = (const float*)d_in[3];
  const float* g1   = (const float*)d_in[4];
  const float* b1   = (const float*)d_in[5];
  const float* g2   = (const float*)d_in[6];
  const float* b2   = (const float*)d_in[7];
  const int*   idx  = (const int*)d_in[8];
  const int*   mask = (const int*)d_in[9];
  float* out = (float*)d_out;

  char* ws = (char*)d_ws;
  double* accum = (double*)ws;
  float*  scal  = (float*)(ws + 64);
  __bf16* Wf    = (__bf16*)(ws + WF_OFF);
  __bf16* x     = (__bf16*)(ws + X_OFF);
  float* ns = out;   // reuse d_out as ns buffer: K3 writes all of it, K5 rewrites in place

  hipMemsetAsync(d_ws, 0, 64, stream);
  k_wprep<<<12, 256, 0, stream>>>(W, Wf);
  k_gemm<<<NODES / NPB, 256, 0, stream>>>(atom, nbr, idx, mask, Wf, bias, accum, x);
  k_fin1<<<1, 1, 0, stream>>>(accum, scal);
  k_act<<<(NODES * F_) / 256, 256, 0, stream>>>(x, mask, g1, b1, scal, accum, ns);
  k_fin2<<<1, 1, 0, stream>>>(accum, scal);
  k_out<<<(NODES * F_) / 256, 256, 0, stream>>>(atom, ns, g2, b2, scal, out);
}

// Round 3
// 431.850 us; speedup vs baseline: 3.2456x; 1.1539x over previous
//
#include <hip/hip_runtime.h>
#include <hip/hip_bf16.h>

#define B_   512
#define N_   64
#define M_   12
#define F_   64
#define NF_  41
#define NODES (B_*N_)      /* 32768 */
#define ROWS  (NODES*M_)   /* 393216 */
#define NPB   8            /* nodes per block in k_gemm */
#define RPB   (NPB*M_)     /* 96 rows per block */
#define KTOT  169
#define ASTR  200          /* LDS A-row stride in bf16 */
#define CSTR  136          /* LDS C-row stride in bf16 (16B-aligned rows) */

typedef __bf16 bf16x8 __attribute__((ext_vector_type(8)));
typedef float  f32x4  __attribute__((ext_vector_type(4)));

/* workspace layout:
   [0,64):        double accum[8]  (s1, ss1, cnz1, cm1, s2, ss2, c2)
   [64,128):      unused
   [128,49280):   bf16 Wf — fragment-ordered W  (6*8*64*8 elems)
   [49280, +ROWS*128*2): bf16 total_gated (masked)                  */
#define WF_OFF 128
#define X_OFF  49280

__device__ __forceinline__ float waveReduce(float v) {
#pragma unroll
  for (int off = 32; off > 0; off >>= 1) v += __shfl_down(v, off, 64);
  return v;
}

/* ------- K0: W (fp32, row-major 169x128) -> fragment-ordered bf16 ------- */
__global__ void k_wprep(const float* __restrict__ W, __bf16* __restrict__ Wf) {
  int t = blockIdx.x * 256 + threadIdx.x;
  if (t >= 6 * 8 * 64) return;
  int lane = t & 63, nt = (t >> 6) & 7, kc = t >> 9;
  int n  = nt * 16 + (lane & 15);
  int k0 = kc * 32 + (lane >> 4) * 8;
  bf16x8 v;
#pragma unroll
  for (int j = 0; j < 8; j++) {
    int k = k0 + j;
    v[j] = (k < KTOT) ? (__bf16)W[k * 128 + n] : (__bf16)0.f;
  }
  *reinterpret_cast<bf16x8*>(&Wf[(size_t)t * 8]) = v;
}

/* ---------------- K1: gather + concat + MFMA GEMM + mask + stats ------------- */
__global__ __launch_bounds__(256, 4) void k_gemm(
    const float* __restrict__ atom, const float* __restrict__ nbr,
    const int* __restrict__ idx, const int* __restrict__ mask,
    const __bf16* __restrict__ Wf, const float* __restrict__ bias,
    double* __restrict__ accum, __bf16* __restrict__ xout)
{
  __shared__ __bf16 As[RPB * ASTR];   // 38400 B; C-tile (96x136 bf16) overlays it later
  __shared__ int    idx_s[RPB];
  __shared__ float  red[4][4];

  const int tid = threadIdx.x;
  const int g0  = blockIdx.x * NPB;
  const int bb  = (g0 >> 6) << 6;     // b * N_  (block never crosses a batch)

  if (tid < RPB) idx_s[tid] = idx[g0 * M_ + tid];
  __syncthreads();

  // stage own-atom part, k in [0,64)
  for (int e = tid; e < RPB * 16; e += 256) {
    int r = e >> 4, k4 = e & 15;
    int node = r / M_;
    float4 v = *(const float4*)&atom[(size_t)(g0 + node) * F_ + k4 * 4];
    __bf16 h[4] = {(__bf16)v.x, (__bf16)v.y, (__bf16)v.z, (__bf16)v.w};
    *reinterpret_cast<uint2*>(&As[r * ASTR + k4 * 4]) = *reinterpret_cast<uint2*>(h);
  }
  // stage gathered-atom part, k in [64,128)
  for (int e = tid; e < RPB * 16; e += 256) {
    int r = e >> 4, k4 = e & 15;
    float4 v = *(const float4*)&atom[(size_t)(bb + idx_s[r]) * F_ + k4 * 4];
    __bf16 h[4] = {(__bf16)v.x, (__bf16)v.y, (__bf16)v.z, (__bf16)v.w};
    *reinterpret_cast<uint2*>(&As[r * ASTR + 64 + k4 * 4]) = *reinterpret_cast<uint2*>(h);
  }
  // stage nbr_fea part, k in [128,169)
  for (int e = tid; e < RPB * NF_; e += 256) {
    int r = e / NF_, k = e - r * NF_;
    As[r * ASTR + 128 + k] = (__bf16)nbr[(size_t)(g0 * M_ + r) * NF_ + k];
  }
  // zero pad k in [169,192)
  for (int e = tid; e < RPB * 32; e += 256) {
    int r = e >> 5, k = 168 + (e & 31);
    if (k >= KTOT) As[r * ASTR + k] = (__bf16)0.f;
  }
  __syncthreads();

  const int w    = tid >> 6;          // wave id: owns nt = {2w, 2w+1}
  const int lane = tid & 63;
  const int nlo  = lane & 15;
  const int quad = lane >> 4;

  f32x4 acc[6][2];
#pragma unroll
  for (int mt = 0; mt < 6; mt++)
#pragma unroll
    for (int j = 0; j < 2; j++) acc[mt][j] = (f32x4){0.f, 0.f, 0.f, 0.f};

#pragma unroll
  for (int kc = 0; kc < 6; kc++) {
    bf16x8 bf[2];
#pragma unroll
    for (int j = 0; j < 2; j++) {
      int nt = 2 * w + j;
      bf[j] = *reinterpret_cast<const bf16x8*>(&Wf[(size_t)(((kc * 8 + nt) * 64) + lane) * 8]);
    }
#pragma unroll
    for (int mt = 0; mt < 6; mt++) {
      bf16x8 af = *reinterpret_cast<const bf16x8*>(
          &As[(mt * 16 + nlo) * ASTR + kc * 32 + quad * 8]);
#pragma unroll
      for (int j = 0; j < 2; j++)
        acc[mt][j] = __builtin_amdgcn_mfma_f32_16x16x32_bf16(af, bf[j], acc[mt][j], 0, 0, 0);
    }
  }

  // ---- dump C tile (bias-added, bf16) into LDS for vectorized masked store ----
  float bv[2];
#pragma unroll
  for (int j = 0; j < 2; j++) bv[j] = bias[(2 * w + j) * 16 + nlo];

  __syncthreads();                    // all A-frag reads done; safe to overlay
  __bf16* Cs = As;
#pragma unroll
  for (int mt = 0; mt < 6; mt++)
#pragma unroll
    for (int reg = 0; reg < 4; reg++)
#pragma unroll
      for (int j = 0; j < 2; j++) {
        int row = mt * 16 + quad * 4 + reg;
        int col = (2 * w + j) * 16 + nlo;
        Cs[row * CSTR + col] = (__bf16)(acc[mt][j][reg] + bv[j]);
      }
  __syncthreads();

  // ---- vectorized mask + stats + store: 6 chunks of 8 per thread ----
  float s = 0.f, ss = 0.f, cz = 0.f, cm = 0.f;
#pragma unroll
  for (int i = 0; i < 6; i++) {
    int ch = tid + i * 256;           // 0..1535
    int row = ch >> 4, c = ch & 15;
    size_t grow = (size_t)(g0 * M_) + row;
    bf16x8 yv = *reinterpret_cast<const bf16x8*>(&Cs[row * CSTR + c * 8]);
    const int4 mA = *(const int4*)&mask[grow * 128 + c * 8];
    const int4 mB = *(const int4*)&mask[grow * 128 + c * 8 + 4];
    int mv[8] = {mA.x, mA.y, mA.z, mA.w, mB.x, mB.y, mB.z, mB.w};
#pragma unroll
    for (int j = 0; j < 8; j++) {
      float y = (float)yv[j];
      if (!mv[j]) { y = 0.f; yv[j] = (__bf16)0.f; }
      s += y; ss += y * y;
      cz += (y != 0.f) ? 1.f : 0.f;
      cm += (float)mv[j];
    }
    *reinterpret_cast<bf16x8*>(&xout[grow * 128 + c * 8]) = yv;
  }

  float v0 = waveReduce(s), v1 = waveReduce(ss), v2 = waveReduce(cz), v3 = waveReduce(cm);
  if (lane == 0) { red[0][w] = v0; red[1][w] = v1; red[2][w] = v2; red[3][w] = v3; }
  __syncthreads();
  if (tid < 4) {
    float t = red[tid][0] + red[tid][1] + red[tid][2] + red[tid][3];
    atomicAdd(&accum[tid], (double)t);
  }
}

/* ------- K3: BN1-apply + sigmoid*softplus + sum over M + stats2 (fin1 fused) ------- */
__global__ __launch_bounds__(256) void k_act(
    const __bf16* __restrict__ x, const int* __restrict__ mask,
    const float* __restrict__ g1, const float* __restrict__ b1,
    double* __restrict__ accum, float* __restrict__ ns)
{
  __shared__ float red[3][4];
  int t = blockIdx.x * 256 + threadIdx.x;    // 0 .. NODES*8-1
  int g = t >> 3, o0 = (t & 7) * 8;

  // inline fin1
  double S = accum[0], SS = accum[1], CNZ = accum[2], CM = accum[3];
  float mu1 = 0.f, inv1 = 0.f;
  if (CNZ > 0.5) {
    double mu = S / CNZ;
    double var = (SS - 2.0 * mu * S + mu * mu * CM) / CNZ;
    mu1 = (float)mu; inv1 = (float)(1.0 / sqrt(var + 1e-5));
  }

  float kf[8], cf[8], kc[8], cc[8];
#pragma unroll
  for (int j = 0; j < 8; j++) {
    kf[j] = inv1 * g1[o0 + j];      cf[j] = b1[o0 + j]      - mu1 * kf[j];
    kc[j] = inv1 * g1[64 + o0 + j]; cc[j] = b1[64 + o0 + j] - mu1 * kc[j];
  }

  size_t base = (size_t)g * (M_ * 128) + o0;
  float ssum[8];
#pragma unroll
  for (int j = 0; j < 8; j++) ssum[j] = 0.f;

#pragma unroll
  for (int m = 0; m < M_; m++) {
    bf16x8 xf = *reinterpret_cast<const bf16x8*>(&x[base + m * 128]);
    bf16x8 xc = *reinterpret_cast<const bf16x8*>(&x[base + m * 128 + 64]);
#pragma unroll
    for (int j = 0; j < 8; j++) {
      float vf = (float)xf[j], vc = (float)xc[j];
      // x==0 <=> masked-out (stored exact 0); bn applies only where mask=1
      float yf = (vf != 0.f) ? fmaf(vf, kf[j], cf[j]) : 0.f;
      float yc = (vc != 0.f) ? fmaf(vc, kc[j], cc[j]) : 0.f;
      float sg = __builtin_amdgcn_rcpf(1.f + __expf(-yf));
      float sp = fmaxf(yc, 0.f) + __logf(1.f + __expf(-fabsf(yc)));
      ssum[j] += sg * sp;   // masked-out contributes sigmoid(0)*softplus(0), per ref
    }
  }

  const int4 mA = *(const int4*)&mask[(size_t)g * (M_ * 128) + o0];
  const int4 mB = *(const int4*)&mask[(size_t)g * (M_ * 128) + o0 + 4];
  int mn[8] = {mA.x, mA.y, mA.z, mA.w, mB.x, mB.y, mB.z, mB.w};
  float s = 0.f, ss2 = 0.f, c = 0.f;
  float v[8];
#pragma unroll
  for (int j = 0; j < 8; j++) {
    v[j] = mn[j] ? ssum[j] : 0.f;
    s += v[j]; ss2 += v[j] * v[j];
    c += (v[j] != 0.f) ? 1.f : 0.f;
  }
  *(float4*)&ns[(size_t)g * 64 + o0]     = (float4){v[0], v[1], v[2], v[3]};
  *(float4*)&ns[(size_t)g * 64 + o0 + 4] = (float4){v[4], v[5], v[6], v[7]};

  float v0 = waveReduce(s), v1 = waveReduce(ss2), v2 = waveReduce(c);
  int lane = threadIdx.x & 63, wid = threadIdx.x >> 6;
  if (lane == 0) { red[0][wid] = v0; red[1][wid] = v1; red[2][wid] = v2; }
  __syncthreads();
  if (threadIdx.x < 3) {
    float r = red[threadIdx.x][0] + red[threadIdx.x][1] + red[threadIdx.x][2] + red[threadIdx.x][3];
    atomicAdd(&accum[4 + threadIdx.x], (double)r);
  }
}

/* ---------------- K5: BN2-apply + residual softplus (fin2 fused) ---------------- */
__global__ __launch_bounds__(256) void k_out(
    const float* __restrict__ atom, const float* __restrict__ ns,
    const float* __restrict__ g2, const float* __restrict__ b2,
    const double* __restrict__ accum, float* __restrict__ out)
{
  int t = blockIdx.x * 256 + threadIdx.x;
  int g = t >> 3, o0 = (t & 7) * 8;

  // inline fin2
  double S = accum[4], SS = accum[5], C = accum[6];
  float mu2 = 0.f, inv2 = 0.f;
  if (C > 0.5) {
    double mu = S / C;
    double var = (SS - 2.0 * mu * S + mu * mu * C) / C;
    mu2 = (float)mu; inv2 = (float)(1.0 / sqrt(var + 1e-5));
  }

  float4 n0 = *(const float4*)&ns[(size_t)g * 64 + o0];
  float4 n1 = *(const float4*)&ns[(size_t)g * 64 + o0 + 4];
  float4 a0 = *(const float4*)&atom[(size_t)g * 64 + o0];
  float4 a1 = *(const float4*)&atom[(size_t)g * 64 + o0 + 4];
  float nv[8] = {n0.x, n0.y, n0.z, n0.w, n1.x, n1.y, n1.z, n1.w};
  float av[8] = {a0.x, a0.y, a0.z, a0.w, a1.x, a1.y, a1.z, a1.w};
  float r[8];
#pragma unroll
  for (int j = 0; j < 8; j++) {
    r[j] = 0.f;
    if (nv[j] != 0.f) {   // ns != 0 <=> m_node == 1 (gated strictly > 0)
      float bn = (nv[j] - mu2) * inv2 * g2[o0 + j] + b2[o0 + j];
      float a = av[j] + bn;
      r[j] = fmaxf(a, 0.f) + __logf(1.f + __expf(-fabsf(a)));
    }
  }
  *(float4*)&out[(size_t)g * 64 + o0]     = (float4){r[0], r[1], r[2], r[3]};
  *(float4*)&out[(size_t)g * 64 + o0 + 4] = (float4){r[4], r[5], r[6], r[7]};
}

extern "C" void kernel_launch(void* const* d_in, const int* in_sizes, int n_in,
                              void* d_out, int out_size, void* d_ws, size_t ws_size,
                              hipStream_t stream)
{
  const float* atom = (const float*)d_in[0];
  const float* nbr  = (const float*)d_in[1];
  const float* W    = (const float*)d_in[2];
  const float* bias = (const float*)d_in[3];
  const float* g1   = (const float*)d_in[4];
  const float* b1   = (const float*)d_in[5];
  const float* g2   = (const float*)d_in[6];
  const float* b2   = (const float*)d_in[7];
  const int*   idx  = (const int*)d_in[8];
  const int*   mask = (const int*)d_in[9];
  float* out = (float*)d_out;

  char* ws = (char*)d_ws;
  double* accum = (double*)ws;
  __bf16* Wf    = (__bf16*)(ws + WF_OFF);
  __bf16* x     = (__bf16*)(ws + X_OFF);
  float* ns = out;   // reuse d_out: k_act writes all of it, k_out rewrites in place

  hipMemsetAsync(d_ws, 0, 64, stream);
  k_wprep<<<12, 256, 0, stream>>>(W, Wf);
  k_gemm<<<NODES / NPB, 256, 0, stream>>>(atom, nbr, idx, mask, Wf, bias, accum, x);
  k_act<<<(NODES * 8) / 256, 256, 0, stream>>>(x, mask, g1, b1, accum, ns);
  k_out<<<(NODES * 8) / 256, 256, 0, stream>>>(atom, ns, g2, b2, accum, out);
}